// Round 6
// baseline (222.763 us; speedup 1.0000x reference)
//
#include <hip/hip_runtime.h>

// MassConservingLSTMCell — round 6: 4-wave blocks (2 blocks/CU, decorrelated),
// VGPR headroom for intact dist-2 B prefetch, split prep kernels for profiling
// visibility. B=1024, U=256, F=31, D=288 (9 k-chunks of 32).
//
//  k_prepW  : 774 blocks — W -> bf16 fragment images (LDS transpose)
//  k_prepF  : 24 blocks  — features -> bf16 A images (16) + zero cell_sys (8)
//  k_heavyR6: 512 blocks x 256 thr — block 64 rows x 256 cols x 8 u;
//             4 waves (col quarters), wave tile 64x64 = 4mt x 4nt.
//             A LDS-resident, B global->reg dist-2, barrier-free K-loop.
//  k_post   : 16 blocks — gates MFMA + final combine.

#define EPS_L1 1e-7f

constexpr int BB  = 1024;
constexpr int U   = 256;
constexpr int F   = 31;
constexpr int D   = 1 + U + F;      // 288
constexpr int NBV = BB * U;         // 262144
constexpr int NCH = D / 32;         // 9
constexpr int UIMGB = NCH * 16384;  // 147456 B per u-slice B-image
constexpr size_t WTB_BYTES  = (size_t)258 * UIMGB;
constexpr size_t FEAT_BYTES = (size_t)BB * D * 2;
constexpr int PITCH = 260;

typedef float f32x4 __attribute__((ext_vector_type(4)));
typedef short bf16x8 __attribute__((ext_vector_type(8)));

__device__ __forceinline__ unsigned f2bf(float x) {
  union { float f; unsigned u; } v; v.f = x;
  unsigned r = v.u + 0x7FFFu + ((v.u >> 16) & 1u);
  return r >> 16;
}

#define GLDS16(gp, lp)                                                        \
  __builtin_amdgcn_global_load_lds(                                          \
      (const __attribute__((address_space(1))) void*)(gp),                   \
      (__attribute__((address_space(3))) void*)(lp), 16, 0, 0)

#define MFMA16(a, b, c) __builtin_amdgcn_mfma_f32_16x16x32_bf16((a), (b), (c), 0, 0, 0)

// ---------------------------------------------------------------- k_prepW
__global__ __launch_bounds__(256) void k_prepW(
    const float* __restrict__ Wi, const float* __restrict__ Wr,
    const float* __restrict__ Wo, short* __restrict__ WtB) {
  __shared__ short lds[2][32 * PITCH];
  const int bid = blockIdx.x, t = threadIdx.x;
  const int u = bid / 3, part = bid % 3;
  const float* src; long ld;
  if (u < 256)       { src = Wr + (size_t)u * 256; ld = 65536; }
  else if (u == 256) { src = Wi; ld = 256; }
  else               { src = Wo; ld = 256; }
  short* dst = WtB + (size_t)u * 73728;
  const int lane = t & 63, wave = t >> 6;
  const int g = lane >> 4, l15 = lane & 15;

#pragma unroll
  for (int cc = 0; cc < 3; ++cc) {
    const int c = part * 3 + cc;
    short* buf = lds[cc & 1];
#pragma unroll
    for (int i = 0; i < 8; ++i) {
      const int f = i * 256 + t;
      const int row = f >> 6, col4 = f & 63;
      const float4 v = *(const float4*)(src + (size_t)(c * 32 + row) * ld + col4 * 4);
      const unsigned lo = f2bf(v.x) | (f2bf(v.y) << 16);
      const unsigned hi = f2bf(v.z) | (f2bf(v.w) << 16);
      unsigned* wp = (unsigned*)&buf[row * PITCH + col4 * 4];
      wp[0] = lo; wp[1] = hi;
    }
    __syncthreads();
#pragma unroll
    for (int i = 0; i < 4; ++i) {
      const int n0 = wave * 4 + i;
      bf16x8 h;
#pragma unroll
      for (int j = 0; j < 8; ++j)
        h[j] = buf[(g * 8 + j) * PITCH + n0 * 16 + l15];
      *(bf16x8*)(dst + (size_t)(c * 16 + n0) * 512 + lane * 8) = h;
    }
    __syncthreads();
  }
}

// ---------------------------------------------------------------- k_prepF
__global__ __launch_bounds__(256) void k_prepF(
    const float* __restrict__ lc, const float* __restrict__ p,
    const float* __restrict__ other, short* __restrict__ featImg,
    float* __restrict__ cell_sys) {
  __shared__ float inv_s[64];
  const int bid = blockIdx.x, t = threadIdx.x;
  if (bid < 16) {
    const int b0 = bid * 64;
    const int row = t >> 2, q = t & 3;
    const float4* lp = (const float4*)(lc + (size_t)(b0 + row) * 256 + q * 64);
    float s = 0.f;
#pragma unroll
    for (int j = 0; j < 16; ++j) {
      const float4 v = lp[j];
      s += fabsf(v.x) + fabsf(v.y) + fabsf(v.z) + fabsf(v.w);
    }
    s += __shfl_xor(s, 1, 64);
    s += __shfl_xor(s, 2, 64);
    if (q == 0) inv_s[row] = 1.f / (s + EPS_L1);
    __syncthreads();
#pragma unroll
    for (int i = 0; i < 9; ++i) {
      const int idx = i * 256 + t;
      const int reg = idx >> 6, l = idx & 63;
      const int c = reg >> 2, mt = reg & 3;
      const int lrow = mt * 16 + (l & 15);
      const int grow = b0 + lrow;
      const int k0 = c * 32 + (l >> 4) * 8;
      bf16x8 h;
#pragma unroll
      for (int j = 0; j < 8; ++j) {
        const int k = k0 + j;
        float v;
        if (k == 0) v = p[grow];
        else if (k <= 256) v = lc[(size_t)grow * 256 + (k - 1)] * inv_s[lrow];
        else v = other[(size_t)grow * 31 + (k - 257)];
        h[j] = (short)f2bf(v);
      }
      *(bf16x8*)(featImg + (size_t)bid * 18432 + (size_t)reg * 512 + l * 8) = h;
    }
  } else {
    float4* cs4 = (float4*)cell_sys;
    const int base = (bid - 16) * 8192 + t;
    const float4 z = {0.f, 0.f, 0.f, 0.f};
#pragma unroll
    for (int k2 = 0; k2 < 32; ++k2) cs4[base + k2 * 256] = z;
  }
}

// ---------------------------------------------------------------- k_heavyR6
// 512 blocks x 256 thr (4 waves). Block: 64 rows x 256 cols x 8 u.
// Wave cq covers cols cq*64..+63 (4 n-tiles), all 64 rows (4 m-tiles).
__global__ __launch_bounds__(256, 2) void k_heavyR6(
    const short* __restrict__ featImg, const short* __restrict__ WtB,
    const float* __restrict__ lc, const float* __restrict__ br,
    float* __restrict__ cell_sys) {
  __shared__ short aT[18432];          // 36864 B: [c][mt][1KB]
  __shared__ float rsum[2][64][4];
  __shared__ float lcs[2][64];

  const int t = threadIdx.x, lane = t & 63, cq = t >> 6;
  const int quad = lane >> 4, l15 = lane & 15;
  const int bid = blockIdx.x;
  const int Mb = (bid >> 3) & 15;                 // 16 M-blocks of 64 rows
  const int ug = (bid & 7) * 4 + (bid >> 7);      // XCD-pinned u-group (0..31)
  const int b0 = Mb * 64, u0 = ug * 8;

  // stage A image (36864 B, linear)
  {
    const char* gA = (const char*)featImg + (size_t)Mb * 36864;
    char* lA = (char*)aT;
#pragma unroll
    for (int i = 0; i < 9; ++i)
      GLDS16(gA + i * 4096 + t * 16, lA + i * 4096 + t * 16);
  }

  const char* aB = (const char*)aT + lane * 16;                 // + c*4096 + mt*1024
  const char* bB = (const char*)WtB + (size_t)u0 * UIMGB + cq * 4096 + lane * 16;

  f32x4 acc[4][4], outa[4][4];
#pragma unroll
  for (int m = 0; m < 4; ++m)
#pragma unroll
    for (int n = 0; n < 4; ++n)
#pragma unroll
      for (int r = 0; r < 4; ++r) { acc[m][n][r] = 0.f; outa[m][n][r] = 0.f; }

  // B dist-2 prefetch: 3-slot static rotation
  bf16x8 bfr[3][4];
#pragma unroll
  for (int n = 0; n < 4; ++n) bfr[0][n] = *(const bf16x8*)(bB + n * 1024);
#pragma unroll
  for (int n = 0; n < 4; ++n) bfr[1][n] = *(const bf16x8*)(bB + 16384 + n * 1024);

  __syncthreads();   // A resident

  // A dist-1 prefetch: 2-slot rotation
  bf16x8 afr[2][4];
#pragma unroll
  for (int m = 0; m < 4; ++m) afr[0][m] = *(const bf16x8*)(aB + m * 1024);

  for (int uu = 0; uu < 8; ++uu) {
    const int u = u0 + uu;
    float bv[4];
#pragma unroll
    for (int n = 0; n < 4; ++n)
      bv[n] = br[(size_t)u * 256 + cq * 64 + n * 16 + l15];
    if (t < 64) lcs[uu & 1][t] = lc[(size_t)(b0 + t) * 256 + u];

#pragma unroll
    for (int c = 0; c < 9; ++c) {
      // B prefetch c+2 (flat across u-images; in-bounds through image 256)
#pragma unroll
      for (int n = 0; n < 4; ++n)
        bfr[(c + 2) % 3][n] = *(const bf16x8*)(bB + (c + 2) * 16384 + n * 1024);
      // A prefetch c+1 (skip at c==8; A[0] reloaded in epilogue)
      if (c < 8) {
#pragma unroll
        for (int m = 0; m < 4; ++m)
          afr[(c + 1) & 1][m] = *(const bf16x8*)(aB + (c + 1) * 4096 + m * 1024);
      }
#pragma unroll
      for (int m = 0; m < 4; ++m)
#pragma unroll
        for (int n = 0; n < 4; ++n)
          acc[m][n] = MFMA16(afr[c & 1][m], bfr[c % 3][n], acc[m][n]);
    }
    bB += UIMGB;

    // next-u A[0] reload, issued under the epilogue
#pragma unroll
    for (int m = 0; m < 4; ++m) afr[0][m] = *(const bf16x8*)(aB + m * 1024);

    // ---- epilogue: bias+relu (into acc), cross-wave rownorm, accumulate
    const int ub = uu & 1;
    float sm[4][4];
#pragma unroll
    for (int m = 0; m < 4; ++m)
#pragma unroll
      for (int r = 0; r < 4; ++r) {
        float sv = 0.f;
#pragma unroll
        for (int n = 0; n < 4; ++n) {
          const float rv = fmaxf(acc[m][n][r] + bv[n], 0.f);
          acc[m][n][r] = rv;
          sv += rv;
        }
        sm[m][r] = sv;
      }
#pragma unroll
    for (int msk = 1; msk < 16; msk <<= 1)
#pragma unroll
      for (int m = 0; m < 4; ++m)
#pragma unroll
        for (int r = 0; r < 4; ++r)
          sm[m][r] += __shfl_xor(sm[m][r], msk, 64);
    if (l15 == 0) {
#pragma unroll
      for (int m = 0; m < 4; ++m)
#pragma unroll
        for (int r = 0; r < 4; ++r)
          rsum[ub][m * 16 + quad * 4 + r][cq] = sm[m][r];
    }
    __syncthreads();
#pragma unroll
    for (int m = 0; m < 4; ++m)
#pragma unroll
      for (int r = 0; r < 4; ++r) {
        const int row = m * 16 + quad * 4 + r;
        const float4 rv = *(const float4*)&rsum[ub][row][0];
        const float tot = (rv.x + rv.y) + (rv.z + rv.w);
        const float alpha = lcs[ub][row] * __builtin_amdgcn_rcpf(tot);
#pragma unroll
        for (int n = 0; n < 4; ++n) {
          outa[m][n][r] = fmaf(alpha, acc[m][n][r], outa[m][n][r]);
          acc[m][n][r] = 0.f;
        }
      }
  }

#pragma unroll
  for (int m = 0; m < 4; ++m)
#pragma unroll
    for (int r = 0; r < 4; ++r) {
      const int grow = b0 + m * 16 + quad * 4 + r;
#pragma unroll
      for (int n = 0; n < 4; ++n)
        atomicAdd(&cell_sys[(size_t)grow * 256 + cq * 64 + n * 16 + l15],
                  outa[m][n][r]);
    }
}

// ---------------------------------------------------------------- k_post
// 16 blocks x 512: gates MFMA (64 rows/block, ig+og in regs) + final combine.
__global__ __launch_bounds__(512, 2) void k_post(
    const short* __restrict__ featImg, const short* __restrict__ WtB,
    const float* __restrict__ bi, const float* __restrict__ bo,
    const float* __restrict__ p, const float* __restrict__ cell_sys,
    float* __restrict__ dout) {
  __shared__ short aT[18432];
  __shared__ float rsum[64][12];
  __shared__ float ps[64];

  const int t = threadIdx.x, lane = t & 63, cg = t >> 6;
  const int quad = lane >> 4, l15 = lane & 15;
  const int mb = blockIdx.x, b0 = mb * 64;

  {
    const char* gsrc = (const char*)featImg + (size_t)mb * 36864;
    char* lbase = (char*)aT;
#pragma unroll
    for (int i = 0; i < 5; ++i) {
      if (i * 8 + cg < 36) {
        const int off = i * 8192 + t * 16;
        GLDS16(gsrc + off, lbase + off);
      }
    }
  }
  if (t < 64) ps[t] = p[b0 + t];

  f32x4 acc[4][2];
#pragma unroll
  for (int mt = 0; mt < 4; ++mt)
#pragma unroll
    for (int n = 0; n < 2; ++n)
#pragma unroll
      for (int r = 0; r < 4; ++r) acc[mt][n][r] = 0.f;

  const char* bptr = (const char*)WtB + (size_t)256 * UIMGB + cg * 2048 + lane * 16;
  bf16x8 cb0 = *(const bf16x8*)(bptr);
  bf16x8 cb1 = *(const bf16x8*)(bptr + 1024);
  bf16x8 nb0 = *(const bf16x8*)(bptr + 16384);
  bf16x8 nb1 = *(const bf16x8*)(bptr + 16384 + 1024);
  bptr += 32768;

  __syncthreads();

  float ig0[4][4], ig1[4][4], og0[4][4], og1[4][4];

#pragma unroll
  for (int g = 0; g < 2; ++g) {
    const float* bias = (g == 0) ? bi : bo;
    const float bv0 = bias[cg * 32 + l15];
    const float bv1 = bias[cg * 32 + 16 + l15];
#pragma unroll
    for (int c = 0; c < 9; ++c) {
      const bf16x8 pb0 = *(const bf16x8*)(bptr);
      const bf16x8 pb1 = *(const bf16x8*)(bptr + 1024);
      bptr += 16384;
      const char* ab = (const char*)aT + c * 4096 + lane * 16;
      const bf16x8 a0 = *(const bf16x8*)(ab);
      const bf16x8 a1 = *(const bf16x8*)(ab + 1024);
      const bf16x8 a2 = *(const bf16x8*)(ab + 2048);
      const bf16x8 a3 = *(const bf16x8*)(ab + 3072);
      acc[0][0] = MFMA16(a0, cb0, acc[0][0]);
      acc[0][1] = MFMA16(a0, cb1, acc[0][1]);
      acc[1][0] = MFMA16(a1, cb0, acc[1][0]);
      acc[1][1] = MFMA16(a1, cb1, acc[1][1]);
      acc[2][0] = MFMA16(a2, cb0, acc[2][0]);
      acc[2][1] = MFMA16(a2, cb1, acc[2][1]);
      acc[3][0] = MFMA16(a3, cb0, acc[3][0]);
      acc[3][1] = MFMA16(a3, cb1, acc[3][1]);
      cb0 = nb0; cb1 = nb1; nb0 = pb0; nb1 = pb1;
    }

#pragma unroll
    for (int mt = 0; mt < 4; ++mt)
#pragma unroll
      for (int r = 0; r < 4; ++r) {
        const float v0 = 1.f / (1.f + __expf(-(acc[mt][0][r] + bv0)));
        const float v1 = 1.f / (1.f + __expf(-(acc[mt][1][r] + bv1)));
        if (g == 0) { ig0[mt][r] = v0; ig1[mt][r] = v1; }
        else        { og0[mt][r] = v0; og1[mt][r] = v1; }
        acc[mt][0][r] = 0.f;
        acc[mt][1][r] = 0.f;
      }

    if (g == 0) {
      float sm[4][4];
#pragma unroll
      for (int mt = 0; mt < 4; ++mt)
#pragma unroll
        for (int r = 0; r < 4; ++r) sm[mt][r] = ig0[mt][r] + ig1[mt][r];
#pragma unroll
      for (int msk = 1; msk < 16; msk <<= 1)
#pragma unroll
        for (int mt = 0; mt < 4; ++mt)
#pragma unroll
          for (int r = 0; r < 4; ++r)
            sm[mt][r] += __shfl_xor(sm[mt][r], msk, 64);
      if (l15 == 0) {
#pragma unroll
        for (int mt = 0; mt < 4; ++mt)
#pragma unroll
          for (int r = 0; r < 4; ++r)
            rsum[mt * 16 + quad * 4 + r][cg] = sm[mt][r];
      }
      __syncthreads();
#pragma unroll
      for (int mt = 0; mt < 4; ++mt)
#pragma unroll
        for (int r = 0; r < 4; ++r) {
          const int row = mt * 16 + quad * 4 + r;
          const float4 ra = *(const float4*)&rsum[row][0];
          const float4 rb = *(const float4*)&rsum[row][4];
          const float inv = 1.f / (((ra.x + ra.y) + (ra.z + ra.w)) +
                                   ((rb.x + rb.y) + (rb.z + rb.w)));
          ig0[mt][r] *= inv;
          ig1[mt][r] *= inv;
        }
    }
  }

#pragma unroll
  for (int mt = 0; mt < 4; ++mt)
#pragma unroll
    for (int r = 0; r < 4; ++r) {
      const int row = mt * 16 + quad * 4 + r;
      const float pr = ps[row];
      const size_t base = (size_t)(b0 + row) * 256 + cg * 32 + l15;
      {
        const float cand = fmaf(ig0[mt][r], pr, cell_sys[base]);
        dout[base] = (1.f - og0[mt][r]) * cand;
        dout[NBV + base] = og0[mt][r] * cand;
      }
      {
        const float cand = fmaf(ig1[mt][r], pr, cell_sys[base + 16]);
        dout[base + 16] = (1.f - og1[mt][r]) * cand;
        dout[NBV + base + 16] = og1[mt][r] * cand;
      }
    }
}

// ---------------------------------------------------------------- launch
extern "C" void kernel_launch(void* const* d_in, const int* in_sizes, int n_in,
                              void* d_out, int out_size, void* d_ws, size_t ws_size,
                              hipStream_t stream) {
  const float* lc    = (const float*)d_in[0];
  const float* p     = (const float*)d_in[1];
  const float* other = (const float*)d_in[2];
  const float* Wi    = (const float*)d_in[3];
  const float* bi    = (const float*)d_in[4];
  const float* Wr    = (const float*)d_in[5];
  const float* br    = (const float*)d_in[6];
  const float* Wo    = (const float*)d_in[7];
  const float* bo    = (const float*)d_in[8];
  float* out = (float*)d_out;

  char* wsb = (char*)d_ws;
  short* WtB      = (short*)wsb;
  short* featImg  = (short*)(wsb + WTB_BYTES);
  float* cell_sys = (float*)(wsb + WTB_BYTES + FEAT_BYTES);

  k_prepW<<<774, 256, 0, stream>>>(Wi, Wr, Wo, WtB);
  k_prepF<<<24, 256, 0, stream>>>(lc, p, other, featImg, cell_sys);
  k_heavyR6<<<512, 256, 0, stream>>>(featImg, WtB, lc, br, cell_sys);
  k_post<<<16, 512, 0, stream>>>(featImg, WtB, bi, bo, p, cell_sys, out);
}